// Round 1
// baseline (76.884 us; speedup 1.0000x reference)
//
#include <hip/hip_runtime.h>
#include <math.h>

// MotionBlur: out = p0*Vtop + p1*Vbot + p3*Hleft + p2*Hright (8-tap box sums each)
// x: [64,1,512,512] f32; logits,gumbel: [1,4] f32; out: [64,1,512,512] f32.

#define IMG   512
#define TH    64
#define TW    64
#define XROWS 79          // 64 + 7 + 8
#define XPITCH 81         // odd-ish pitch: phase A/B LDS reads are <=2-way aliased (free)
#define OVPITCH 65

__global__ __launch_bounds__(256, 2) void motion_blur_kernel(
    const float* __restrict__ x,
    const float* __restrict__ logits,
    const float* __restrict__ gnoise,
    float* __restrict__ out)
{
    __shared__ float Xl[XROWS * XPITCH];   // 79*81*4B = 25.6 KB
    __shared__ float OV[TH * OVPITCH];     // 64*65*4B = 16.6 KB

    const int t    = threadIdx.x;
    const int bid  = blockIdx.x;
    const int img  = bid >> 6;             // 64 tiles per image (8x8)
    const int tile = bid & 63;
    const int y0   = (tile >> 3) << 6;
    const int x0   = (tile & 7) << 6;

    // gumbel-softmax probs (tau=1): softmax(logits + noise). Cheap, per-thread.
    float l0 = logits[0] + gnoise[0];
    float l1 = logits[1] + gnoise[1];
    float l2 = logits[2] + gnoise[2];
    float l3 = logits[3] + gnoise[3];
    float mx = fmaxf(fmaxf(l0, l1), fmaxf(l2, l3));
    float e0 = expf(l0 - mx), e1 = expf(l1 - mx);
    float e2 = expf(l2 - mx), e3 = expf(l3 - mx);
    float inv = 1.0f / (e0 + e1 + e2 + e3);
    const float p0 = e0 * inv;  // north: rows y-7..y
    const float p1 = e1 * inv;  // south: rows y+1..y+8
    const float p2 = e2 * inv;  // east:  cols x+1..x+8
    const float p3 = e3 * inv;  // west:  cols x-7..x

    const float* __restrict__ xi = x + (size_t)img * IMG * IMG;

    // ---- stage 79x79 input tile (zero-padded at image borders) ----
    for (int i = t; i < XROWS * XROWS; i += 256) {
        int ry = i / XROWS;            // const divisor -> magic mul
        int cx = i - ry * XROWS;
        int yy = y0 - 7 + ry;
        int xx = x0 - 7 + cx;
        float val = 0.0f;
        if ((unsigned)yy < (unsigned)IMG && (unsigned)xx < (unsigned)IMG)
            val = xi[yy * IMG + xx];
        Xl[ry * XPITCH + cx] = val;
    }
    __syncthreads();

    // ---- phase A: vertical 16-tap (two 8-wide sliding box sums) ----
    {
        const int c  = t & 63;    // output column
        const int rq = t >> 6;    // row quad: rows rq*16 .. rq*16+15
        const int base = (rq * 16) * XPITCH + (c + 7);
        float v[31];
        #pragma unroll
        for (int j = 0; j < 31; ++j) v[j] = Xl[base + j * XPITCH];
        float sa = 0.f, sb = 0.f;
        #pragma unroll
        for (int j = 0; j < 8; ++j) { sa += v[j]; sb += v[j + 8]; }
        #pragma unroll
        for (int i = 0; i < 16; ++i) {
            OV[(rq * 16 + i) * OVPITCH + c] = p0 * sa + p1 * sb;
            if (i < 15) {
                sa += v[i + 8]  - v[i];
                sb += v[i + 16] - v[i + 8];
            }
        }
    }
    __syncthreads();

    // ---- phase B: horizontal 16-tap + combine + store ----
    {
        const int r  = t >> 2;    // output row
        const int xq = t & 3;     // x quad: cols xq*16 .. xq*16+15
        const int base = (r + 7) * XPITCH + xq * 16;
        float v[31];
        #pragma unroll
        for (int j = 0; j < 31; ++j) v[j] = Xl[base + j];
        float sa = 0.f, sb = 0.f;
        #pragma unroll
        for (int j = 0; j < 8; ++j) { sa += v[j]; sb += v[j + 8]; }
        float res[16];
        #pragma unroll
        for (int i = 0; i < 16; ++i) {
            res[i] = p3 * sa + p2 * sb + OV[r * OVPITCH + xq * 16 + i];
            if (i < 15) {
                sa += v[i + 8]  - v[i];
                sb += v[i + 16] - v[i + 8];
            }
        }
        float* __restrict__ orow =
            out + (size_t)img * IMG * IMG + (size_t)(y0 + r) * IMG + (x0 + xq * 16);
        #pragma unroll
        for (int i = 0; i < 4; ++i) {
            *reinterpret_cast<float4*>(orow + 4 * i) =
                make_float4(res[4*i], res[4*i+1], res[4*i+2], res[4*i+3]);
        }
    }
}

extern "C" void kernel_launch(void* const* d_in, const int* in_sizes, int n_in,
                              void* d_out, int out_size, void* d_ws, size_t ws_size,
                              hipStream_t stream) {
    const float* x      = (const float*)d_in[0];
    const float* logits = (const float*)d_in[1];
    const float* gn     = (const float*)d_in[2];
    float* outp         = (float*)d_out;
    // 64 images x (8x8) tiles of 64x64
    motion_blur_kernel<<<dim3(64 * 64), dim3(256), 0, stream>>>(x, logits, gn, outp);
}

// Round 2
// 39.234 us; speedup vs baseline: 1.9596x; 1.9596x over previous
//
#include <hip/hip_runtime.h>
#include <math.h>

// MotionBlur: out = p0*Vtop + p1*Vbot + p3*Hleft + p2*Hright (8-tap box sums each)
// x: [64,1,512,512] f32; logits,gumbel: [1,4] f32; out: [64,1,512,512] f32.
//
// Tile 64 wide x 32 tall. LDS: Xl 47 rows x 80 floats (f4-swizzled) = 15.0 KB,
// OV 32x65 = 8.3 KB -> 23.4 KB total -> 6 blocks/CU (24 waves, 75% occ).

#define IMG    512
#define TW     64
#define TH     32
#define XR     47      // TH + 15 halo rows (top 7, bottom 8)
#define XC4    20      // 80 floats = TW + 16 halo cols (left 8, right 8)
#define OVP    65

__global__ __launch_bounds__(256, 6) void motion_blur_kernel(
    const float* __restrict__ x,
    const float* __restrict__ logits,
    const float* __restrict__ gnoise,
    float* __restrict__ out)
{
    __shared__ float4 Xl4[XR * XC4];   // 15040 B, f4 col swizzled by (row&3)
    __shared__ float  OV[TH * OVP];    // 8320 B
    float* __restrict__ Xl = reinterpret_cast<float*>(Xl4);

    const int t    = threadIdx.x;
    const int bid  = blockIdx.x;
    const int img  = bid >> 7;           // 128 tiles per image (8 x, 16 y)
    const int tile = bid & 127;
    const int y0   = (tile >> 3) * TH;
    const int x0   = (tile & 7) * TW;

    // gumbel-softmax probs (tau=1): softmax(logits + noise)
    float l0 = logits[0] + gnoise[0];
    float l1 = logits[1] + gnoise[1];
    float l2 = logits[2] + gnoise[2];
    float l3 = logits[3] + gnoise[3];
    float mx = fmaxf(fmaxf(l0, l1), fmaxf(l2, l3));
    float e0 = expf(l0 - mx), e1 = expf(l1 - mx);
    float e2 = expf(l2 - mx), e3 = expf(l3 - mx);
    float inv = 1.0f / (e0 + e1 + e2 + e3);
    const float p0 = e0 * inv;  // north: rows y-7..y
    const float p1 = e1 * inv;  // south: rows y+1..y+8
    const float p2 = e2 * inv;  // east:  cols x+1..x+8
    const float p3 = e3 * inv;  // west:  cols x-7..x

    const float4* __restrict__ xi4 =
        reinterpret_cast<const float4*>(x + (size_t)img * IMG * IMG);

    // ---- stage 47 x 80 floats as float4, zero-padded at borders ----
    // padded row ry <-> image row y0-7+ry; padded f4 col c4 <-> image f4 col x0/4-2+c4
    {
        const int gx4base = (x0 >> 2) - 2;
        for (int i = t; i < XR * XC4; i += 256) {
            int ry = i / XC4;              // const divisor -> magic mul
            int c4 = i - ry * XC4;
            int yy = y0 - 7 + ry;
            int g4 = gx4base + c4;
            float4 v = make_float4(0.f, 0.f, 0.f, 0.f);
            if ((unsigned)yy < (unsigned)IMG && (unsigned)g4 < (unsigned)(IMG / 4))
                v = xi4[yy * (IMG / 4) + g4];
            Xl4[ry * XC4 + (c4 ^ (ry & 3))] = v;   // swizzled store, 16B aligned
        }
    }
    __syncthreads();

    // ---- phase A: vertical 2x8-tap. thread: column c=t&63, rows rq*8..rq*8+7 ----
    {
        const int c   = t & 63;
        const int rq  = t >> 6;
        const int cc  = c + 8;             // padded float col
        const int clo = cc & 3;
        const int cb  = cc & ~3;
        float v[23];
        #pragma unroll
        for (int j = 0; j < 23; ++j) {
            // prow = rq*8 + j; (prow&3) == (j&3) since rq*8 is a multiple of 4
            v[j] = Xl[(rq * 8 + j) * 80 + (cb ^ ((j & 3) << 2)) + clo];
        }
        float sa = 0.f, sb = 0.f;
        #pragma unroll
        for (int j = 0; j < 8; ++j) { sa += v[j]; sb += v[j + 8]; }
        #pragma unroll
        for (int i = 0; i < 8; ++i) {
            OV[(rq * 8 + i) * OVP + c] = p0 * sa + p1 * sb;
            if (i < 7) {
                sa += v[i + 8]  - v[i];
                sb += v[i + 16] - v[i + 8];
            }
        }
    }
    __syncthreads();

    // ---- phase B: horizontal 2x8-tap + combine + store ----
    // thread: row r=t>>3 (0..31), cols xq*8..xq*8+7 (xq=t&7)
    {
        const int r  = t >> 3;
        const int xq = t & 7;
        const int pr = r + 7;              // padded row
        const int m4 = pr & 3;             // swizzle mask for this row
        float v[24];                       // padded cols 8*xq .. 8*xq+23
        #pragma unroll
        for (int k = 0; k < 6; ++k) {
            float4 q = Xl4[pr * XC4 + ((2 * xq + k) ^ m4)];
            v[4 * k + 0] = q.x;
            v[4 * k + 1] = q.y;
            v[4 * k + 2] = q.z;
            v[4 * k + 3] = q.w;
        }
        // v[j] <-> image col x0 + 8*xq + j - 8. Output col i: west v[i+1..i+8],
        // east v[i+9..i+16].
        float sa = 0.f, sb = 0.f;
        #pragma unroll
        for (int j = 1; j <= 8; ++j)  sa += v[j];
        #pragma unroll
        for (int j = 9; j <= 16; ++j) sb += v[j];
        float res[8];
        #pragma unroll
        for (int i = 0; i < 8; ++i) {
            res[i] = p3 * sa + p2 * sb + OV[r * OVP + xq * 8 + i];
            if (i < 7) {
                sa += v[i + 9]  - v[i + 1];
                sb += v[i + 17] - v[i + 9];
            }
        }
        float* __restrict__ orow =
            out + (size_t)img * IMG * IMG + (size_t)(y0 + r) * IMG + (x0 + xq * 8);
        *reinterpret_cast<float4*>(orow)     = make_float4(res[0], res[1], res[2], res[3]);
        *reinterpret_cast<float4*>(orow + 4) = make_float4(res[4], res[5], res[6], res[7]);
    }
}

extern "C" void kernel_launch(void* const* d_in, const int* in_sizes, int n_in,
                              void* d_out, int out_size, void* d_ws, size_t ws_size,
                              hipStream_t stream) {
    const float* x      = (const float*)d_in[0];
    const float* logits = (const float*)d_in[1];
    const float* gn     = (const float*)d_in[2];
    float* outp         = (float*)d_out;
    // 64 images x (8x16) tiles of 64x32
    motion_blur_kernel<<<dim3(64 * 128), dim3(256), 0, stream>>>(x, logits, gn, outp);
}

// Round 3
// 37.885 us; speedup vs baseline: 2.0294x; 1.0356x over previous
//
#include <hip/hip_runtime.h>
#include <math.h>

// MotionBlur: out = p0*Vtop + p1*Vbot + p3*Hleft + p2*Hright (8-tap box sums).
// x: [64,1,512,512] f32; logits,gumbel: [1,4] f32; out: [64,1,512,512] f32.
//
// LDS-free streaming structure: wave = 256 cols (64 lanes x float4) x 16 rows.
// Vertical sums via 16-deep register FIFO + rolling VA/VB. Horizontal sums via
// intra-lane prefix + cross-lane shuffles (ds_bpermute), edge lanes fetch the
// 8-col halo from global (L2-resident). No __shared__, no barriers.

#define IMG   512
#define IMG4  128   // float4s per row

static __device__ __forceinline__ float4 f4z() {
    return make_float4(0.f, 0.f, 0.f, 0.f);
}

__global__ __launch_bounds__(256, 4) void motion_blur_kernel(
    const float* __restrict__ x,
    const float* __restrict__ logits,
    const float* __restrict__ gnoise,
    float* __restrict__ out)
{
    const int t    = threadIdx.x;
    const int lane = t & 63;
    const int wv   = t >> 6;

    // XCD-chunk swizzle: 1024 blocks, 8 XCDs -> 128 contiguous logical per XCD
    // (vertically adjacent bands + both column tiles of an image share an L2).
    const int bid  = blockIdx.x;
    const int lbid = (bid & 7) * 128 + (bid >> 3);

    const int img = lbid >> 4;        // 16 blocks per image
    const int rem = lbid & 15;
    const int ct  = rem >> 3;         // column tile 0/1 (256 cols each)
    const int bb  = rem & 7;          // 64-row block band; wave adds 16-row sub-band
    const int y0  = bb * 64 + wv * 16;
    const int c4t = ct * 64;          // tile base in float4 units
    const int c4  = c4t + lane;       // this lane's float4 column block

    // gumbel-softmax probs (tau=1): softmax(logits + noise)
    float l0 = logits[0] + gnoise[0];
    float l1 = logits[1] + gnoise[1];
    float l2 = logits[2] + gnoise[2];
    float l3 = logits[3] + gnoise[3];
    float mx = fmaxf(fmaxf(l0, l1), fmaxf(l2, l3));
    float e0 = expf(l0 - mx), e1 = expf(l1 - mx);
    float e2 = expf(l2 - mx), e3 = expf(l3 - mx);
    float inv = 1.0f / (e0 + e1 + e2 + e3);
    const float p0  = e0 * inv;   // north: rows y-7..y
    const float p1  = e1 * inv;   // south: rows y+1..y+8
    const float p2  = e2 * inv;   // east:  cols x+1..x+8
    const float p3  = e3 * inv;   // west:  cols x-7..x
    const float q32 = p3 - p2;
    const float np3 = -p3;

    const float4* __restrict__ xi4 =
        reinterpret_cast<const float4*>(x) + (size_t)img * (IMG * IMG4);

    // Horizontal halo: lane 0 -> block -2, lane 1 -> block -1,
    // lane 62 -> block +64, lane 63 -> block +65 (relative to tile base).
    const int  hc4   = c4t + ((lane < 2) ? (lane - 2) : (lane + 2));
    const bool hlane = (lane < 2) || (lane >= 62);
    const bool hok   = hlane && ((unsigned)hc4 < (unsigned)IMG4);

    const int lm2 = (lane - 2) & 63;
    const int lm1 = (lane - 1) & 63;
    const int lp1 = (lane + 1) & 63;
    const int lp2 = (lane + 2) & 63;

    // ---- warm-up: rows y0-7 .. y0+8 into FIFO slot (row & 15) ----
    float4 fifo[16];
    #pragma unroll
    for (int k = 0; k < 16; ++k) {
        const int r = y0 - 7 + k;
        float4 v = f4z();
        if ((unsigned)r < (unsigned)IMG) v = xi4[r * IMG4 + c4];
        fifo[(9 + k) & 15] = v;
    }
    float4 VA = f4z(), VB = f4z();
    #pragma unroll
    for (int k = 0; k < 8; ++k) {   // rows y0-7..y0 -> slots 9..15,0
        const float4 v = fifo[(9 + k) & 15];
        VA.x += v.x; VA.y += v.y; VA.z += v.z; VA.w += v.w;
    }
    #pragma unroll
    for (int k = 0; k < 8; ++k) {   // rows y0+1..y0+8 -> slots 1..8
        const float4 v = fifo[(1 + k) & 15];
        VB.x += v.x; VB.y += v.y; VB.z += v.z; VB.w += v.w;
    }

    // ---- 4-deep main-load pipeline: rows y0+9..y0+12 ----
    float4 pre[4];
    #pragma unroll
    for (int k = 0; k < 4; ++k) {
        const int r = y0 + 9 + k;
        float4 v = f4z();
        if (r < IMG) v = xi4[r * IMG4 + c4];
        pre[k] = v;
    }

    float* __restrict__ obase =
        out + (size_t)img * (IMG * IMG) + (size_t)y0 * IMG + 4 * c4;

    #pragma unroll
    for (int i = 0; i < 16; ++i) {
        // keep VMEM in program order across iterations (reg-pressure control);
        // ALU may cross (mask 0x7 = ALU|VALU|SALU).
        __builtin_amdgcn_sched_barrier(0x7);

        const int y = y0 + i;
        // halo row load (4 lanes, L2-resident neighbor-tile data)
        float4 hv = f4z();
        if (hok) hv = xi4[y * IMG4 + hc4];

        const float4 cur = fifo[i & 15];
        // intra-block inclusive prefix
        const float L0 = cur.x;
        const float L1 = L0 + cur.y;
        const float L2 = L1 + cur.z;
        const float L3 = L2 + cur.w;
        const float hL0 = hv.x;
        const float hL1 = hL0 + hv.y;
        const float hL2 = hL1 + hv.z;
        const float hL3 = hL2 + hv.w;

        // L of block x-2 (west halo via own halo regs on lanes 0,1)
        float Lm0 = __shfl(L0, lm2), Lm1 = __shfl(L1, lm2),
              Lm2_ = __shfl(L2, lm2), Lm3 = __shfl(L3, lm2);
        if (lane < 2) { Lm0 = hL0; Lm1 = hL1; Lm2_ = hL2; Lm3 = hL3; }
        // L of block x+2 (east halo on lanes 62,63)
        float Lp0 = __shfl(L0, lp2), Lp1 = __shfl(L1, lp2),
              Lp2_ = __shfl(L2, lp2), Lp3 = __shfl(L3, lp2);
        if (lane >= 62) { Lp0 = hL0; Lp1 = hL1; Lp2_ = hL2; Lp3 = hL3; }
        // block sums of x-1 / x+1
        float sm1 = __shfl(L3, lm1);
        const float sm1h = __shfl(hL3, 1);    // lane 1's halo = block -1
        if (lane == 0) sm1 = sm1h;
        float sp1 = __shfl(L3, lp1);
        const float sp1h = __shfl(hL3, 62);   // lane 62's halo = block +64
        if (lane == 63) sp1 = sp1h;

        // W_i = (Lm3 + sm1) + L_i - Lm_i ; E_i = (L3 + sp1) + Lp_i - L_i
        const float base = p3 * (Lm3 + sm1) + p2 * (L3 + sp1);
        float4 r4;
        r4.x = fmaf(p0, VA.x, fmaf(p1, VB.x,
                 fmaf(q32, L0, fmaf(np3, Lm0, fmaf(p2, Lp0, base)))));
        r4.y = fmaf(p0, VA.y, fmaf(p1, VB.y,
                 fmaf(q32, L1, fmaf(np3, Lm1, fmaf(p2, Lp1, base)))));
        r4.z = fmaf(p0, VA.z, fmaf(p1, VB.z,
                 fmaf(q32, L2, fmaf(np3, Lm2_, fmaf(p2, Lp2_, base)))));
        r4.w = fmaf(p0, VA.w, fmaf(p1, VB.w,
                 fmaf(q32, L3, fmaf(np3, Lm3, fmaf(p2, Lp3, base)))));
        *reinterpret_cast<float4*>(obase + (size_t)i * IMG) = r4;

        if (i < 15) {
            // step vertical window y -> y+1
            const float4 vnew = pre[i & 3];            // row y+9
            const float4 a = fifo[(i + 1) & 15];       // row y+1
            const float4 b = fifo[(i + 9) & 15];       // row y-7 (leaving)
            VA.x += a.x - b.x; VA.y += a.y - b.y;
            VA.z += a.z - b.z; VA.w += a.w - b.w;
            VB.x += vnew.x - a.x; VB.y += vnew.y - a.y;
            VB.z += vnew.z - a.z; VB.w += vnew.w - a.w;
            fifo[(i + 9) & 15] = vnew;
            if (i <= 10) {                             // refill for iter i+4
                const int r = y0 + 13 + i;
                float4 v = f4z();
                if (r < IMG) v = xi4[r * IMG4 + c4];
                pre[i & 3] = v;
            }
        }
    }
}

extern "C" void kernel_launch(void* const* d_in, const int* in_sizes, int n_in,
                              void* d_out, int out_size, void* d_ws, size_t ws_size,
                              hipStream_t stream) {
    const float* x      = (const float*)d_in[0];
    const float* logits = (const float*)d_in[1];
    const float* gn     = (const float*)d_in[2];
    float* outp         = (float*)d_out;
    // 64 images x 2 column tiles x 8 block bands = 1024 blocks of 4 waves
    motion_blur_kernel<<<dim3(1024), dim3(256), 0, stream>>>(x, logits, gn, outp);
}